// Round 5
// baseline (488.154 us; speedup 1.0000x reference)
//
#include <hip/hip_runtime.h>
#include <math.h>
#include <stdint.h>

#define B_ 4
#define L_ 2048
#define D_ 1024
#define H_ 16

typedef __attribute__((ext_vector_type(4))) float f32x4;
typedef __attribute__((ext_vector_type(2))) float f32x2;
typedef __attribute__((ext_vector_type(8))) short s16x8;
typedef __attribute__((ext_vector_type(4))) short s16x4;
typedef __attribute__((ext_vector_type(4))) unsigned short u16x4;
typedef __attribute__((ext_vector_type(4))) unsigned int u32x4;
typedef __attribute__((ext_vector_type(2))) __bf16 bf16x2;

__device__ __forceinline__ unsigned short f2bf(float f) {
  unsigned int u = __float_as_uint(f);
  u += 0x7fffu + ((u >> 16) & 1u);  // RNE
  return (unsigned short)(u >> 16);
}
__device__ __forceinline__ float b2f(unsigned short s) {
  return __uint_as_float(((unsigned int)s) << 16);
}
// packed f32x2 -> bf16x2 (RTNE); lowers to v_cvt_pk_bf16_f32 on gfx950
__device__ __forceinline__ unsigned int pk2(float a, float b) {
  f32x2 v;
  v[0] = a;
  v[1] = b;
  bf16x2 r = __builtin_convertvector(v, bf16x2);
  return __builtin_bit_cast(unsigned int, r);
}
// silu via fast rcp (1-ulp)
__device__ __forceinline__ float silu_fast(float v) {
  return v * __builtin_amdgcn_rcpf(1.0f + __expf(-v));
}
// async global->LDS DMA, 16B per lane; lds dest = wave-uniform base + lane*16
__device__ __forceinline__ void gl_lds16(const void* g, void* l) {
  __builtin_amdgcn_global_load_lds(
      (__attribute__((address_space(1))) void*)(uintptr_t)g,
      (__attribute__((address_space(3))) void*)(uint32_t)(uintptr_t)l, 16, 0, 0);
}

// ---------------------------------------------------------------------------
// fp32 -> bf16 elementwise (x)
// ---------------------------------------------------------------------------
__global__ __launch_bounds__(256) void conv_x(const float* __restrict__ x,
                                              unsigned short* __restrict__ xb, int n4) {
  int i = blockIdx.x * 256 + threadIdx.x;
  if (i < n4) {
    f32x4 v = *(const f32x4*)(x + (size_t)i * 4);
    u16x4 o;
#pragma unroll
    for (int j = 0; j < 4; ++j) o[j] = f2bf(v[j]);
    *(u16x4*)(xb + (size_t)i * 4) = o;
  }
}

// ---------------------------------------------------------------------------
// W[K][N] fp32 -> Wt[N][K] bf16 (LDS tile transpose)
// ---------------------------------------------------------------------------
__global__ __launch_bounds__(256) void trans_w(const float* __restrict__ W,
                                               unsigned short* __restrict__ Wt,
                                               int K, int N) {
  __shared__ float T[64][65];
  const int k0 = blockIdx.y * 64, n0 = blockIdx.x * 64;
  const int tid = threadIdx.x;
#pragma unroll
  for (int i = 0; i < 16; ++i) {
    int e = tid + i * 256;
    int r = e >> 6, c = e & 63;
    T[r][c] = W[(size_t)(k0 + r) * N + n0 + c];
  }
  __syncthreads();
#pragma unroll
  for (int i = 0; i < 16; ++i) {
    int e = tid + i * 256;
    int r = e >> 6, c = e & 63;
    Wt[(size_t)(n0 + r) * K + k0 + c] = f2bf(T[c][r]);
  }
}

// ---------------------------------------------------------------------------
// RoPE cos/sin table [L][32]
// ---------------------------------------------------------------------------
__global__ __launch_bounds__(256) void rope_tab(f32x2* __restrict__ tab) {
  int i = blockIdx.x * 256 + threadIdx.x;  // L_*32
  int l = i >> 5, j = i & 31;
  float inv = expf(-(float)j * (9.210340371976184f / 32.0f));  // 10000^(-j/32)
  float ang = (float)l * inv;
  f32x2 cs;
  cs[0] = cosf(ang);
  cs[1] = sinf(ang);
  tab[i] = cs;
}

// ---------------------------------------------------------------------------
// bf16 MFMA GEMM: C = [silu](A @ Bt^T).  T1 XCD-aware block swizzle (kept:
// round-4 showed non-attn time improved ~14us with it).
// ---------------------------------------------------------------------------
template <int MODE>
__global__ __launch_bounds__(256) void gemm_bf16(const unsigned short* __restrict__ A,
                                                 const unsigned short* __restrict__ Bt,
                                                 void* __restrict__ Cp,
                                                 int M, int N, int K) {
  alignas(16) __shared__ unsigned short As[128][32];
  alignas(16) __shared__ unsigned short Bs[128][32];
  const int tid = threadIdx.x;
  const int lane = tid & 63, w = tid >> 6;
  const int quad = lane >> 4, l15 = lane & 15;
  const int wr = w >> 1, wc = w & 1;
  // XCD swizzle: physical wgid -> chunked logical id (8 XCDs round-robin)
  const int nwg = gridDim.x * gridDim.y;
  const int wgid = blockIdx.y * gridDim.x + blockIdx.x;
  const int swz = (wgid & 7) * (nwg >> 3) + (wgid >> 3);
  const int m0 = (swz / gridDim.x) * 128, n0 = (swz % gridDim.x) * 128;
  const int srow = lane >> 2;
  const int schunk = (lane & 3) ^ ((lane >> 3) & 3);
  const int fcol = (quad ^ ((l15 >> 1) & 3)) * 8;
  f32x4 acc[4][4] = {};
  for (int k0 = 0; k0 < K; k0 += 32) {
    __syncthreads();
#pragma unroll
    for (int i = 0; i < 2; ++i) {
      int r0 = (w * 2 + i) * 16;
      gl_lds16(A + (size_t)(m0 + r0 + srow) * K + k0 + schunk * 8, &As[r0][0]);
      gl_lds16(Bt + (size_t)(n0 + r0 + srow) * K + k0 + schunk * 8, &Bs[r0][0]);
    }
    __syncthreads();
    s16x8 af[4], bf[4];
#pragma unroll
    for (int mi = 0; mi < 4; ++mi) af[mi] = *(const s16x8*)&As[wr * 64 + mi * 16 + l15][fcol];
#pragma unroll
    for (int nj = 0; nj < 4; ++nj) bf[nj] = *(const s16x8*)&Bs[wc * 64 + nj * 16 + l15][fcol];
#pragma unroll
    for (int mi = 0; mi < 4; ++mi)
#pragma unroll
      for (int nj = 0; nj < 4; ++nj)
        acc[mi][nj] = __builtin_amdgcn_mfma_f32_16x16x32_bf16(af[mi], bf[nj], acc[mi][nj], 0, 0, 0);
  }
#pragma unroll
  for (int mi = 0; mi < 4; ++mi)
#pragma unroll
    for (int nj = 0; nj < 4; ++nj)
#pragma unroll
      for (int reg = 0; reg < 4; ++reg) {
        int rg = m0 + wr * 64 + mi * 16 + quad * 4 + reg;
        int cg = n0 + wc * 64 + nj * 16 + l15;
        float v = acc[mi][nj][reg];
        if (MODE == 1) {
          ((unsigned short*)Cp)[(size_t)rg * N + cg] = f2bf(silu_fast(v));
        } else {
          ((float*)Cp)[(size_t)rg * N + cg] = v;
        }
      }
}

// ---------------------------------------------------------------------------
// In-place RoPE on q,k quarters of qkuv_bf + build v_t[bh][64 d][Lperm] bf16.
// Key axis of vt is PERMUTED within each 32-group so that P fragments (C-layout
// of S^T, pairs of 16-key tiles concatenated) form a valid mfma_16x16x32
// A-operand: position p = 8q+4h+j  <-  local key 16h+4q+j.
// ---------------------------------------------------------------------------
__global__ __launch_bounds__(256) void rope_conv(unsigned short* __restrict__ qk,
                                                 unsigned short* __restrict__ vt,
                                                 const f32x2* __restrict__ tab) {
  alignas(16) __shared__ unsigned short Vsh[64][72];
  const int tid = threadIdx.x;
  const int bh = blockIdx.y, b = bh >> 4, h = bh & 15;
  const int l0 = blockIdx.x * 64;
#pragma unroll
  for (int i = 0; i < 2; ++i) {
    int p = tid + i * 256;
    int row = p >> 3, c4 = p & 7;
    int l = l0 + row;
    size_t base = (size_t)(b * L_ + l) * 4096 + h * 64 + c4 * 4;
#pragma unroll
    for (int t = 0; t < 2; ++t) {  // 0: q, 1: k
      size_t o = base + (size_t)t * 1024;
      u16x4 lo = *(u16x4*)(qk + o);
      u16x4 hi = *(u16x4*)(qk + o + 32);
      u16x4 nlo, nhi;
#pragma unroll
      for (int jj = 0; jj < 4; ++jj) {
        f32x2 cs = tab[l * 32 + c4 * 4 + jj];
        float fl = b2f(lo[jj]), fh = b2f(hi[jj]);
        nlo[jj] = f2bf(fl * cs[0] - fh * cs[1]);
        nhi[jj] = f2bf(fh * cs[0] + fl * cs[1]);
      }
      *(u16x4*)(qk + o) = nlo;
      *(u16x4*)(qk + o + 32) = nhi;
    }
  }
#pragma unroll
  for (int i = 0; i < 2; ++i) {
    int ch = tid + i * 256;
    int row = ch >> 3, c8 = ch & 7;
    *(s16x8*)&Vsh[row][c8 * 8] =
        *(const s16x8*)(qk + (size_t)(b * L_ + l0 + row) * 4096 + 2048 + h * 64 + c8 * 8);
  }
  __syncthreads();
#pragma unroll
  for (int i = 0; i < 2; ++i) {
    int ch = tid + i * 256;
    int drow = ch >> 3, c8 = ch & 7;
    s16x8 o;
#pragma unroll
    for (int jj = 0; jj < 8; ++jj) {
      int pos = c8 * 8 + jj;  // 0..63 within tile
      int g = pos >> 5, p = pos & 31;
      int lk = g * 32 + ((p >> 2) & 1) * 16 + ((p >> 3) & 3) * 4 + (p & 3);
      o[jj] = (short)Vsh[lk][drow];
    }
    *(s16x8*)(vt + (size_t)(bh * 64 + drow) * 2048 + l0 + c8 * 8) = o;
  }
}

// ---------------------------------------------------------------------------
// Fused MFMA attention v9: T15 SKEWED PIPELINE.
// Per iteration i: QK(i) || epilogue(i-1) || PV(i-1).  The epilogue no longer
// depends on this iteration's MFMA results, so its VALU/trans ops fill the QK
// MFMA shadow (diagnosis: 4 rounds showed the wall is each wave's serial
// QK->epi->PV chain, not occupancy/trans/memory-latency).
// Staging (one barrier/iter, all latencies ~1 full iteration):
//   top of iter i (after barrier): stage K(i+1)->Kb[(i+1)&1], V(i)->Vb[i&1]
//   K(i) read iter i; V(i) read iter i+1; masks(i) loaded mid-iter i after
//   epi(i-1) frees the registers, consumed iter i+1.
// Blocks of 64 q-rows (wave owns 16) keep two sacc copies within ~110 VGPR.
// ---------------------------------------------------------------------------
__global__ __launch_bounds__(256) void attn_mfma(
    const unsigned short* __restrict__ qk, const unsigned short* __restrict__ vt,
    const float* __restrict__ amask, const float* __restrict__ cmask,
    const float* __restrict__ cbias, const float* __restrict__ gamma,
    const float* __restrict__ beta, unsigned short* __restrict__ attng) {
  alignas(16) __shared__ unsigned short Kb[2][64][64];  // [slot][key][d] XOR-8 chunks
  alignas(16) __shared__ unsigned short Vb[2][64][64];  // [slot][d][key] XOR-8 chunks
  const int tid = threadIdx.x;
  const int lane = tid & 63, w = tid >> 6;
  const int quad = lane >> 4, l15 = lane & 15;
  const int bh = blockIdx.y, b = bh >> 4, h = bh & 15;
  const int l0 = blockIdx.x * 64;  // 64 q-rows/block; wave w owns 16
  const float cb = cbias[h];
  const int srow = lane >> 3;            // 0..7 within a 1KB DMA
  const int schunk = (lane & 7) ^ srow;  // source chunk for XOR-8 store

  // Q fragments for this wave's 16 q-rows (b-operand of S^T mfma)
  s16x8 qf[2];
  const int qg = l0 + w * 16 + l15;
#pragma unroll
  for (int s = 0; s < 2; ++s)
    qf[s] = *(const s16x8*)(qk + (size_t)(b * L_ + qg) * 4096 + h * 64 + s * 32 + quad * 8);
  const float* abase = amask + ((size_t)b * L_ + qg) * L_;
  const float* cbase = cmask + (size_t)b * L_;

  f32x4 oacc[4] = {};   // [dt] C-layout: row=q=quad*4+reg, col=d=dt*16+l15
  f32x4 cmcb[4], am4[4];  // masks for tile i, consumed in iter i+1

  auto stageK = [&](int slot, int m0) {
#pragma unroll
    for (int i = 0; i < 2; ++i) {
      int r0 = w * 16 + i * 8;
      gl_lds16(qk + (size_t)(b * L_ + m0 + r0 + srow) * 4096 + 1024 + h * 64 + schunk * 8,
               &Kb[slot][r0][0]);
    }
  };
  auto stageV = [&](int slot, int m0) {
#pragma unroll
    for (int i = 0; i < 2; ++i) {
      int r0 = w * 16 + i * 8;
      gl_lds16(vt + (size_t)(bh * 64 + r0 + srow) * 2048 + m0 + schunk * 8, &Vb[slot][r0][0]);
    }
  };
  auto qkt = [&](int slot, f32x4 (&sacc)[4]) {
#pragma unroll
    for (int kt = 0; kt < 4; ++kt) sacc[kt] = f32x4{0.f, 0.f, 0.f, 0.f};
#pragma unroll
    for (int s = 0; s < 2; ++s) {
      s16x8 kf[4];
#pragma unroll
      for (int kt = 0; kt < 4; ++kt)
        kf[kt] = *(const s16x8*)&Kb[slot][kt * 16 + l15][((s * 4 + quad) ^ (l15 & 7)) * 8];
      __builtin_amdgcn_s_setprio(1);
#pragma unroll
      for (int kt = 0; kt < 4; ++kt)
        sacc[kt] = __builtin_amdgcn_mfma_f32_16x16x32_bf16(kf[kt], qf[s], sacc[kt], 0, 0, 0);
      __builtin_amdgcn_s_setprio(0);
    }
  };
  auto epi = [&](const f32x4 (&sacc)[4], s16x8 (&pf)[2]) {
#pragma unroll
    for (int t = 0; t < 2; ++t) {
      u32x4 pw;
#pragma unroll
      for (int half = 0; half < 2; ++half) {
        int kt = 2 * t + half;
        float x[4];
#pragma unroll
        for (int r = 0; r < 4; ++r) {
          float v = fmaf(sacc[kt][r], 0.125f, cmcb[kt][r]);
          v = silu_fast(v);
          x[r] = v * am4[kt][r];
        }
        pw[half * 2 + 0] = pk2(x[0], x[1]);
        pw[half * 2 + 1] = pk2(x[2], x[3]);
      }
      pf[t] = __builtin_bit_cast(s16x8, pw);
    }
  };
  auto ldmasks = [&](int m0) {
#pragma unroll
    for (int kt = 0; kt < 4; ++kt) {
      cmcb[kt] = *(const f32x4*)(cbase + m0 + kt * 16 + quad * 4) * cb;
      am4[kt] = *(const f32x4*)(abase + m0 + kt * 16 + quad * 4);
    }
  };
  auto pv = [&](int slot, const s16x8 (&pf)[2]) {
#pragma unroll
    for (int dt = 0; dt < 4; ++dt)
#pragma unroll
      for (int t = 0; t < 2; ++t) {
        s16x8 vf = *(const s16x8*)&Vb[slot][dt * 16 + l15][((t * 4 + quad) ^ (l15 & 7)) * 8];
        __builtin_amdgcn_s_setprio(1);
        oacc[dt] = __builtin_amdgcn_mfma_f32_16x16x32_bf16(pf[t], vf, oacc[dt], 0, 0, 0);
        __builtin_amdgcn_s_setprio(0);
      }
  };

  f32x4 sA[4], sB[4];  // two live S-tiles (named: rule-20 static indexing)

  // --- prologue: K(0) in flight ---
  stageK(0, 0);
  // --- iter 0 (cur=0): QK(0); no prev ---
  __syncthreads();  // drain K(0)
  stageK(1, 64);
  stageV(0, 0);
  qkt(0, sA);
  ldmasks(0);
  // --- pairs: iters (1+2p, 2+2p), p=0..14  (covers i=1..30) ---
  for (int p = 0; p < 15; ++p) {
    const int i = 1 + 2 * p;
    // odd iter i (cur=1): QK(i)->sB, epi/PV of i-1 from sA
    __syncthreads();  // drain K(i)->Kb1, V(i-1)->Vb0
    stageK(0, (i + 1) * 64);
    stageV(1, i * 64);
    qkt(1, sB);
    {
      s16x8 pf[2];
      epi(sA, pf);
      ldmasks(i * 64);
      pv(0, pf);
    }
    // even iter i+1 (cur=0): QK(i+1)->sA, epi/PV of i from sB
    __syncthreads();  // drain K(i+1)->Kb0, V(i)->Vb1
    stageK(1, (i + 2) * 64);
    stageV(0, (i + 1) * 64);
    qkt(0, sA);
    {
      s16x8 pf[2];
      epi(sB, pf);
      ldmasks((i + 1) * 64);
      pv(1, pf);
    }
  }
  // --- iter 31 (cur=1): QK(31)->sB, epi/PV of 30 from sA; no K(32) ---
  __syncthreads();  // drain K(31)->Kb1, V(30)->Vb0
  stageV(1, 31 * 64);
  qkt(1, sB);
  {
    s16x8 pf[2];
    epi(sA, pf);
    ldmasks(31 * 64);
    pv(0, pf);
  }
  // --- tail: epi/PV of 31 from sB ---
  __syncthreads();  // drain V(31)->Vb1
  {
    s16x8 pf[2];
    epi(sB, pf);
    pv(1, pf);
  }

  // LayerNorm over d=64 + u-gate + store
  {
    float sm[4], sq[4];
#pragma unroll
    for (int reg = 0; reg < 4; ++reg) {
      float s1 = 0.f, s2 = 0.f;
#pragma unroll
      for (int dt = 0; dt < 4; ++dt) {
        float v = oacc[dt][reg];
        s1 += v;
        s2 += v * v;
      }
      sm[reg] = s1;
      sq[reg] = s2;
    }
#pragma unroll
    for (int m = 1; m < 16; m <<= 1) {
#pragma unroll
      for (int reg = 0; reg < 4; ++reg) {
        sm[reg] += __shfl_xor(sm[reg], m);
        sq[reg] += __shfl_xor(sq[reg], m);
      }
    }
    float mu[4], rs[4];
#pragma unroll
    for (int reg = 0; reg < 4; ++reg) {
      mu[reg] = sm[reg] * (1.0f / 64.0f);
      float var = sq[reg] * (1.0f / 64.0f) - mu[reg] * mu[reg];
      rs[reg] = rsqrtf(var + 1e-5f);
    }
#pragma unroll
    for (int dt = 0; dt < 4; ++dt) {
      float g = gamma[dt * 16 + l15], be = beta[dt * 16 + l15];
#pragma unroll
      for (int reg = 0; reg < 4; ++reg) {
        int rowg = l0 + w * 16 + quad * 4 + reg;
        int colg = dt * 16 + l15;
        float v = (oacc[dt][reg] - mu[reg]) * rs[reg] * g + be;
        float u = b2f(qk[(size_t)(b * L_ + rowg) * 4096 + 3072 + h * 64 + colg]);
        attng[(size_t)(b * L_ + rowg) * 1024 + h * 64 + colg] = f2bf(v * u);
      }
    }
  }
}

extern "C" void kernel_launch(void* const* d_in, const int* in_sizes, int n_in,
                              void* d_out, int out_size, void* d_ws, size_t ws_size,
                              hipStream_t stream) {
  const float* x = (const float*)d_in[0];
  const float* amask = (const float*)d_in[1];
  const float* cmask = (const float*)d_in[2];
  const float* Wqkuv = (const float*)d_in[3];
  const float* Wout = (const float*)d_in[4];
  const float* gamma = (const float*)d_in[5];
  const float* beta = (const float*)d_in[6];
  const float* cbias = (const float*)d_in[7];
  float* out = (float*)d_out;

  char* ws = (char*)d_ws;
  unsigned short* qkuv_bf = (unsigned short*)ws;                    // 64 MB
  unsigned short* vt = (unsigned short*)(ws + ((size_t)64 << 20));  // 16 MB
  unsigned short* xbf = (unsigned short*)(ws + ((size_t)80 << 20));  // 16 MB
  unsigned short* Wt = (unsigned short*)(ws + ((size_t)96 << 20));   // 8 MB
  unsigned short* Wot = (unsigned short*)(ws + ((size_t)104 << 20)); // 2 MB
  unsigned short* attng = (unsigned short*)(ws + ((size_t)106 << 20)); // 16 MB
  f32x2* tab = (f32x2*)(ws + ((size_t)122 << 20));                   // 0.5 MB

  conv_x<<<8192, 256, 0, stream>>>(x, xbf, (B_ * L_ * D_) / 4);
  trans_w<<<dim3(4096 / 64, 1024 / 64), 256, 0, stream>>>(Wqkuv, Wt, 1024, 4096);
  trans_w<<<dim3(1024 / 64, 1024 / 64), 256, 0, stream>>>(Wout, Wot, 1024, 1024);
  rope_tab<<<(L_ * 32) / 256, 256, 0, stream>>>(tab);

  gemm_bf16<1><<<dim3(4096 / 128, 8192 / 128), 256, 0, stream>>>(xbf, Wt, qkuv_bf,
                                                                 B_ * L_, 4 * D_, D_);
  rope_conv<<<dim3(L_ / 64, B_ * H_), 256, 0, stream>>>(qkuv_bf, vt, tab);
  attn_mfma<<<dim3(L_ / 64, B_ * H_), 256, 0, stream>>>(qkuv_bf, vt, amask, cmask, cbias,
                                                        gamma, beta, attng);
  gemm_bf16<0><<<dim3(1024 / 128, 8192 / 128), 256, 0, stream>>>(attng, Wot, out,
                                                                 B_ * L_, D_, D_);
}

// Round 6
// 458.809 us; speedup vs baseline: 1.0640x; 1.0640x over previous
//
#include <hip/hip_runtime.h>
#include <math.h>
#include <stdint.h>

#define B_ 4
#define L_ 2048
#define D_ 1024
#define H_ 16

typedef __attribute__((ext_vector_type(4))) float f32x4;
typedef __attribute__((ext_vector_type(2))) float f32x2;
typedef __attribute__((ext_vector_type(8))) short s16x8;
typedef __attribute__((ext_vector_type(4))) short s16x4;
typedef __attribute__((ext_vector_type(4))) unsigned short u16x4;
typedef __attribute__((ext_vector_type(4))) unsigned int u32x4;
typedef __attribute__((ext_vector_type(2))) __bf16 bf16x2;

__device__ __forceinline__ unsigned short f2bf(float f) {
  unsigned int u = __float_as_uint(f);
  u += 0x7fffu + ((u >> 16) & 1u);  // RNE
  return (unsigned short)(u >> 16);
}
__device__ __forceinline__ float b2f(unsigned short s) {
  return __uint_as_float(((unsigned int)s) << 16);
}
// packed f32x2 -> bf16x2 (RTNE); lowers to v_cvt_pk_bf16_f32 on gfx950
__device__ __forceinline__ unsigned int pk2(float a, float b) {
  f32x2 v;
  v[0] = a;
  v[1] = b;
  bf16x2 r = __builtin_convertvector(v, bf16x2);
  return __builtin_bit_cast(unsigned int, r);
}
// silu via fast rcp (1-ulp)
__device__ __forceinline__ float silu_fast(float v) {
  return v * __builtin_amdgcn_rcpf(1.0f + __expf(-v));
}
// async global->LDS DMA, 16B per lane; lds dest = wave-uniform base + lane*16
__device__ __forceinline__ void gl_lds16(const void* g, void* l) {
  __builtin_amdgcn_global_load_lds(
      (__attribute__((address_space(1))) void*)(uintptr_t)g,
      (__attribute__((address_space(3))) void*)(uint32_t)(uintptr_t)l, 16, 0, 0);
}

// ---------------------------------------------------------------------------
// fp32 -> bf16 elementwise (x)
// ---------------------------------------------------------------------------
__global__ __launch_bounds__(256) void conv_x(const float* __restrict__ x,
                                              unsigned short* __restrict__ xb, int n4) {
  int i = blockIdx.x * 256 + threadIdx.x;
  if (i < n4) {
    f32x4 v = *(const f32x4*)(x + (size_t)i * 4);
    u16x4 o;
#pragma unroll
    for (int j = 0; j < 4; ++j) o[j] = f2bf(v[j]);
    *(u16x4*)(xb + (size_t)i * 4) = o;
  }
}

// ---------------------------------------------------------------------------
// W[K][N] fp32 -> Wt[N][K] bf16 (LDS tile transpose)
// ---------------------------------------------------------------------------
__global__ __launch_bounds__(256) void trans_w(const float* __restrict__ W,
                                               unsigned short* __restrict__ Wt,
                                               int K, int N) {
  __shared__ float T[64][65];
  const int k0 = blockIdx.y * 64, n0 = blockIdx.x * 64;
  const int tid = threadIdx.x;
#pragma unroll
  for (int i = 0; i < 16; ++i) {
    int e = tid + i * 256;
    int r = e >> 6, c = e & 63;
    T[r][c] = W[(size_t)(k0 + r) * N + n0 + c];
  }
  __syncthreads();
#pragma unroll
  for (int i = 0; i < 16; ++i) {
    int e = tid + i * 256;
    int r = e >> 6, c = e & 63;
    Wt[(size_t)(n0 + r) * K + k0 + c] = f2bf(T[c][r]);
  }
}

// ---------------------------------------------------------------------------
// RoPE cos/sin table [L][32]
// ---------------------------------------------------------------------------
__global__ __launch_bounds__(256) void rope_tab(f32x2* __restrict__ tab) {
  int i = blockIdx.x * 256 + threadIdx.x;  // L_*32
  int l = i >> 5, j = i & 31;
  float inv = expf(-(float)j * (9.210340371976184f / 32.0f));  // 10000^(-j/32)
  float ang = (float)l * inv;
  f32x2 cs;
  cs[0] = cosf(ang);
  cs[1] = sinf(ang);
  tab[i] = cs;
}

// ---------------------------------------------------------------------------
// bf16 MFMA GEMM v2: 8-phase 256x256 tile (learn_hip m198/m201 template).
// C = [silu](A @ Bt^T).  BK=64, 512 threads = 8 waves (2M x 4N), per-wave
// output 128x64 (acc 8x4 frags).  Double-buffered 128KB LDS.  Per phase
// (= one C-quadrant x K=64): 12 ds_read_b128 frag loads || stage-issue ->
// s_barrier -> setprio(1) 16 MFMA setprio(0) -> s_barrier.  Next K-tile's A
// staged in phase 0, B in phase 1 (early issue; ~2.5 phases + 2 barriers of
// latency cover); one vmcnt(0)+barrier per K-tile boundary publishes the
// buffer (race-free: every wave drains its own DMAs before crossing).
// LDS XOR-8 chunk swizzle (phys_chunk = logical ^ (row&7)) ported from the
// attn kernel (same [row][64] geometry; measured 0 bank conflicts).
// XCD-chunked block swizzle kept (round-4: non-attn -14us).
// ---------------------------------------------------------------------------
template <int MODE>
__global__ __launch_bounds__(512) void gemm_bf16(const unsigned short* __restrict__ A,
                                                 const unsigned short* __restrict__ Bt,
                                                 void* __restrict__ Cp,
                                                 int M, int N, int K) {
  alignas(16) __shared__ unsigned short Ash[2][256][64];
  alignas(16) __shared__ unsigned short Bsh[2][256][64];
  const int tid = threadIdx.x;
  const int lane = tid & 63, w = tid >> 6;
  const int quad = lane >> 4, l15 = lane & 15;
  const int wm = w >> 2, wn = w & 3;  // 2 x 4 wave grid
  // XCD swizzle: physical wgid -> chunked logical id (8 XCDs round-robin)
  const int nwg = gridDim.x * gridDim.y;
  const int wgid = blockIdx.y * gridDim.x + blockIdx.x;
  const int swz = (wgid & 7) * (nwg >> 3) + (wgid >> 3);
  const int m0 = (swz / gridDim.x) * 256, n0 = (swz % gridDim.x) * 256;

  // Staging: 4 loads/thread per 32KB array-tile.  Load j of wave w covers
  // rows j*64 + w*8 + (lane>>3), phys chunk lane&7; source chunk XOR'd so
  // LDS[r][kc] holds global chunk kc ^ (r&7).
  const int s_sub = lane >> 3;                  // 0..7 row-within-8
  const int s_src = (lane & 7) ^ s_sub;         // source k-chunk
  auto stage = [&](const unsigned short* __restrict__ G, int row0, int k0,
                   unsigned short (*dst)[64]) {
#pragma unroll
    for (int j = 0; j < 4; ++j) {
      int r = j * 64 + w * 8 + s_sub;
      gl_lds16(G + (size_t)(row0 + r) * K + k0 + s_src * 8, &dst[j * 64 + w * 8][0]);
    }
  };

  f32x4 acc[8][4] = {};
  const int NT = K / 64;

  // prologue: tile 0 fully staged + drained
  stage(A, m0, 0, Ash[0]);
  stage(Bt, n0, 0, Bsh[0]);
  asm volatile("s_waitcnt vmcnt(0)" ::: "memory");
  __builtin_amdgcn_s_barrier();
  __builtin_amdgcn_sched_barrier(0);

  for (int t = 0; t < NT; ++t) {
    const int c = t & 1;
#pragma unroll
    for (int p = 0; p < 4; ++p) {
      const int qa = p & 1, qb = p >> 1;  // quadrant: fm base qa*4, fn base qb*2
      // frag ds_reads (current buffer)
      s16x8 af[4][2], bf[2][2];
#pragma unroll
      for (int i = 0; i < 4; ++i)
#pragma unroll
        for (int ks = 0; ks < 2; ++ks)
          af[i][ks] = *(const s16x8*)&Ash[c][wm * 128 + (qa * 4 + i) * 16 + l15]
                                           [((ks * 4 + quad) ^ (l15 & 7)) * 8];
#pragma unroll
      for (int jn = 0; jn < 2; ++jn)
#pragma unroll
        for (int ks = 0; ks < 2; ++ks)
          bf[jn][ks] = *(const s16x8*)&Bsh[c][wn * 64 + (qb * 2 + jn) * 16 + l15]
                                            [((ks * 4 + quad) ^ (l15 & 7)) * 8];
      // early-issue next-tile staging into the opposite buffer
      if (t + 1 < NT) {
        if (p == 0) stage(A, m0, (t + 1) * 64, Ash[c ^ 1]);
        if (p == 1) stage(Bt, n0, (t + 1) * 64, Bsh[c ^ 1]);
      }
      __builtin_amdgcn_sched_barrier(0);
      __builtin_amdgcn_s_barrier();
      __builtin_amdgcn_sched_barrier(0);
      __builtin_amdgcn_s_setprio(1);
#pragma unroll
      for (int i = 0; i < 4; ++i)
#pragma unroll
        for (int jn = 0; jn < 2; ++jn)
#pragma unroll
          for (int ks = 0; ks < 2; ++ks)
            acc[qa * 4 + i][qb * 2 + jn] = __builtin_amdgcn_mfma_f32_16x16x32_bf16(
                af[i][ks], bf[jn][ks], acc[qa * 4 + i][qb * 2 + jn], 0, 0, 0);
      __builtin_amdgcn_s_setprio(0);
      if (p < 3) {
        __builtin_amdgcn_s_barrier();
        __builtin_amdgcn_sched_barrier(0);
      }
    }
    // K-tile boundary: own DMAs drained, then block-wide publish
    if (t + 1 < NT) {
      asm volatile("s_waitcnt vmcnt(0)" ::: "memory");
    }
    __builtin_amdgcn_s_barrier();
    __builtin_amdgcn_sched_barrier(0);
  }

#pragma unroll
  for (int fm = 0; fm < 8; ++fm)
#pragma unroll
    for (int fn = 0; fn < 4; ++fn)
#pragma unroll
      for (int reg = 0; reg < 4; ++reg) {
        int rg = m0 + wm * 128 + fm * 16 + quad * 4 + reg;
        int cg = n0 + wn * 64 + fn * 16 + l15;
        float v = acc[fm][fn][reg];
        if (MODE == 1) {
          ((unsigned short*)Cp)[(size_t)rg * N + cg] = f2bf(silu_fast(v));
        } else {
          ((float*)Cp)[(size_t)rg * N + cg] = v;
        }
      }
}

// ---------------------------------------------------------------------------
// In-place RoPE on q,k quarters of qkuv_bf + build v_t[bh][64 d][Lperm] bf16.
// Key axis of vt is PERMUTED within each 32-group so that P fragments (C-layout
// of S^T, pairs of 16-key tiles concatenated) form a valid mfma_16x16x32
// A-operand: position p = 8q+4h+j  <-  local key 16h+4q+j.
// ---------------------------------------------------------------------------
__global__ __launch_bounds__(256) void rope_conv(unsigned short* __restrict__ qk,
                                                 unsigned short* __restrict__ vt,
                                                 const f32x2* __restrict__ tab) {
  alignas(16) __shared__ unsigned short Vsh[64][72];
  const int tid = threadIdx.x;
  const int bh = blockIdx.y, b = bh >> 4, h = bh & 15;
  const int l0 = blockIdx.x * 64;
#pragma unroll
  for (int i = 0; i < 2; ++i) {
    int p = tid + i * 256;
    int row = p >> 3, c4 = p & 7;
    int l = l0 + row;
    size_t base = (size_t)(b * L_ + l) * 4096 + h * 64 + c4 * 4;
#pragma unroll
    for (int t = 0; t < 2; ++t) {  // 0: q, 1: k
      size_t o = base + (size_t)t * 1024;
      u16x4 lo = *(u16x4*)(qk + o);
      u16x4 hi = *(u16x4*)(qk + o + 32);
      u16x4 nlo, nhi;
#pragma unroll
      for (int jj = 0; jj < 4; ++jj) {
        f32x2 cs = tab[l * 32 + c4 * 4 + jj];
        float fl = b2f(lo[jj]), fh = b2f(hi[jj]);
        nlo[jj] = f2bf(fl * cs[0] - fh * cs[1]);
        nhi[jj] = f2bf(fh * cs[0] + fl * cs[1]);
      }
      *(u16x4*)(qk + o) = nlo;
      *(u16x4*)(qk + o + 32) = nhi;
    }
  }
#pragma unroll
  for (int i = 0; i < 2; ++i) {
    int ch = tid + i * 256;
    int row = ch >> 3, c8 = ch & 7;
    *(s16x8*)&Vsh[row][c8 * 8] =
        *(const s16x8*)(qk + (size_t)(b * L_ + l0 + row) * 4096 + 2048 + h * 64 + c8 * 8);
  }
  __syncthreads();
#pragma unroll
  for (int i = 0; i < 2; ++i) {
    int ch = tid + i * 256;
    int drow = ch >> 3, c8 = ch & 7;
    s16x8 o;
#pragma unroll
    for (int jj = 0; jj < 8; ++jj) {
      int pos = c8 * 8 + jj;  // 0..63 within tile
      int g = pos >> 5, p = pos & 31;
      int lk = g * 32 + ((p >> 2) & 1) * 16 + ((p >> 3) & 3) * 4 + (p & 3);
      o[jj] = (short)Vsh[lk][drow];
    }
    *(s16x8*)(vt + (size_t)(bh * 64 + drow) * 2048 + l0 + c8 * 8) = o;
  }
}

// ---------------------------------------------------------------------------
// Fused MFMA attention v4 (round-0 exact revert — measured 203us; six probe
// rounds showed it at a local optimum: dbuf/mask-prefetch/trans-batching/
// occupancy/skew all null-to-negative).
// ---------------------------------------------------------------------------
__global__ __launch_bounds__(256) void attn_mfma(
    const unsigned short* __restrict__ qk, const unsigned short* __restrict__ vt,
    const float* __restrict__ amask, const float* __restrict__ cmask,
    const float* __restrict__ cbias, const float* __restrict__ gamma,
    const float* __restrict__ beta, unsigned short* __restrict__ attng) {
  alignas(16) __shared__ unsigned short Ks[64][64];   // [key][d], d-chunks XORed
  alignas(16) __shared__ unsigned short Vts[64][64];  // [d][key], key-chunks XORed
  const int tid = threadIdx.x;
  const int lane = tid & 63, w = tid >> 6;
  const int quad = lane >> 4, l15 = lane & 15;
  const int bh = blockIdx.y, b = bh >> 4, h = bh & 15;
  const int l0 = blockIdx.x * 128;
  const float cb = cbias[h];
  const int srow = lane >> 3;            // 0..7 within a 1KB DMA
  const int schunk = (lane & 7) ^ srow;  // source chunk for XOR-8 store

  // Hoist Q fragments for this wave's 32 q-rows (b-operand of S^T mfma)
  s16x8 qf[2][2];
  const float* abase[2];
#pragma unroll
  for (int qs = 0; qs < 2; ++qs) {
    int qg = l0 + w * 32 + qs * 16 + l15;
#pragma unroll
    for (int s = 0; s < 2; ++s)
      qf[qs][s] = *(const s16x8*)(qk + (size_t)(b * L_ + qg) * 4096 + h * 64 + s * 32 + quad * 8);
    abase[qs] = amask + ((size_t)b * L_ + qg) * L_;
  }
  const float* cbase = cmask + (size_t)b * L_;

  f32x4 oacc[2][4] = {};  // [qs][dt] C-layout: row=q=quad*4+reg, col=d=dt*16+l15

  for (int m0 = 0; m0 < L_; m0 += 64) {
    __syncthreads();  // prev-iter LDS reads complete before DMA overwrite
#pragma unroll
    for (int i = 0; i < 2; ++i) {  // wave w stages rows w*16+i*8 .. +7
      int r0 = w * 16 + i * 8;
      gl_lds16(qk + (size_t)(b * L_ + m0 + r0 + srow) * 4096 + 1024 + h * 64 + schunk * 8,
               &Ks[r0][0]);
      gl_lds16(vt + (size_t)(bh * 64 + r0 + srow) * 2048 + m0 + schunk * 8, &Vts[r0][0]);
    }
    // Masks: one vaddr per qs, 4 imm-offset loads each
    f32x4 cmcb[4], am4[2][4];
#pragma unroll
    for (int kt = 0; kt < 4; ++kt)
      cmcb[kt] = *(const f32x4*)(cbase + m0 + kt * 16 + quad * 4) * cb;
#pragma unroll
    for (int qs = 0; qs < 2; ++qs)
#pragma unroll
      for (int kt = 0; kt < 4; ++kt)
        am4[qs][kt] = *(const f32x4*)(abase[qs] + m0 + kt * 16 + quad * 4);
    __syncthreads();  // vmcnt(0) drain -> DMA + mask loads complete

    // S^T = K @ Q^T over d=64 (two K=32 steps)
    f32x4 sacc[2][4] = {};  // [qs][kt]; C: key=quad*4+reg, q=l15
#pragma unroll
    for (int s = 0; s < 2; ++s) {
      s16x8 kf[4];
#pragma unroll
      for (int kt = 0; kt < 4; ++kt)
        kf[kt] = *(const s16x8*)&Ks[kt * 16 + l15][((s * 4 + quad) ^ (l15 & 7)) * 8];
      __builtin_amdgcn_s_setprio(1);
#pragma unroll
      for (int qs = 0; qs < 2; ++qs)
#pragma unroll
        for (int kt = 0; kt < 4; ++kt)
          sacc[qs][kt] = __builtin_amdgcn_mfma_f32_16x16x32_bf16(kf[kt], qf[qs][s],
                                                                 sacc[qs][kt], 0, 0, 0);
      __builtin_amdgcn_s_setprio(0);
    }

    // Epilogue -> P fragments packed as K=32 A-operands (kt pairs)
    s16x8 pf[2][2];
#pragma unroll
    for (int qs = 0; qs < 2; ++qs)
#pragma unroll
      for (int t = 0; t < 2; ++t) {
        u32x4 pw;
#pragma unroll
        for (int half = 0; half < 2; ++half) {
          int kt = 2 * t + half;
          float x[4];
#pragma unroll
          for (int r = 0; r < 4; ++r) {
            float v = fmaf(sacc[qs][kt][r], 0.125f, cmcb[kt][r]);
            v = silu_fast(v);
            x[r] = v * am4[qs][kt][r];
          }
          pw[half * 2 + 0] = pk2(x[0], x[1]);
          pw[half * 2 + 1] = pk2(x[2], x[3]);
        }
        pf[qs][t] = __builtin_bit_cast(s16x8, pw);
      }

    // O += P @ V, K=32 per group (vt key-permuted to match P's lane layout)
#pragma unroll
    for (int dt = 0; dt < 4; ++dt)
#pragma unroll
      for (int t = 0; t < 2; ++t) {
        s16x8 vf = *(const s16x8*)&Vts[dt * 16 + l15][((t * 4 + quad) ^ (l15 & 7)) * 8];
        __builtin_amdgcn_s_setprio(1);
#pragma unroll
        for (int qs = 0; qs < 2; ++qs)
          oacc[qs][dt] = __builtin_amdgcn_mfma_f32_16x16x32_bf16(pf[qs][t], vf,
                                                                 oacc[qs][dt], 0, 0, 0);
        __builtin_amdgcn_s_setprio(0);
      }
  }

  // LayerNorm over d=64 + u-gate + store
#pragma unroll
  for (int qs = 0; qs < 2; ++qs) {
    float sm[4], sq[4];
#pragma unroll
    for (int reg = 0; reg < 4; ++reg) {
      float s1 = 0.f, s2 = 0.f;
#pragma unroll
      for (int dt = 0; dt < 4; ++dt) {
        float v = oacc[qs][dt][reg];
        s1 += v;
        s2 += v * v;
      }
      sm[reg] = s1;
      sq[reg] = s2;
    }
#pragma unroll
    for (int m = 1; m < 16; m <<= 1) {
#pragma unroll
      for (int reg = 0; reg < 4; ++reg) {
        sm[reg] += __shfl_xor(sm[reg], m);
        sq[reg] += __shfl_xor(sq[reg], m);
      }
    }
    float mu[4], rs[4];
#pragma unroll
    for (int reg = 0; reg < 4; ++reg) {
      mu[reg] = sm[reg] * (1.0f / 64.0f);
      float var = sq[reg] * (1.0f / 64.0f) - mu[reg] * mu[reg];
      rs[reg] = rsqrtf(var + 1e-5f);
    }
#pragma unroll
    for (int dt = 0; dt < 4; ++dt) {
      float g = gamma[dt * 16 + l15], be = beta[dt * 16 + l15];
#pragma unroll
      for (int reg = 0; reg < 4; ++reg) {
        int rowg = l0 + w * 32 + qs * 16 + quad * 4 + reg;
        int colg = dt * 16 + l15;
        float v = (oacc[qs][dt][reg] - mu[reg]) * rs[reg] * g + be;
        float u = b2f(qk[(size_t)(b * L_ + rowg) * 4096 + 3072 + h * 64 + colg]);
        attng[(size_t)(b * L_ + rowg) * 1024 + h * 64 + colg] = f2bf(v * u);
      }
    }
  }
}

extern "C" void kernel_launch(void* const* d_in, const int* in_sizes, int n_in,
                              void* d_out, int out_size, void* d_ws, size_t ws_size,
                              hipStream_t stream) {
  const float* x = (const float*)d_in[0];
  const float* amask = (const float*)d_in[1];
  const float* cmask = (const float*)d_in[2];
  const float* Wqkuv = (const float*)d_in[3];
  const float* Wout = (const float*)d_in[4];
  const float* gamma = (const float*)d_in[5];
  const float* beta = (const float*)d_in[6];
  const float* cbias = (const float*)d_in[7];
  float* out = (float*)d_out;

  char* ws = (char*)d_ws;
  unsigned short* qkuv_bf = (unsigned short*)ws;                    // 64 MB
  unsigned short* vt = (unsigned short*)(ws + ((size_t)64 << 20));  // 16 MB
  unsigned short* xbf = (unsigned short*)(ws + ((size_t)80 << 20));  // 16 MB
  unsigned short* Wt = (unsigned short*)(ws + ((size_t)96 << 20));   // 8 MB
  unsigned short* Wot = (unsigned short*)(ws + ((size_t)104 << 20)); // 2 MB
  unsigned short* attng = (unsigned short*)(ws + ((size_t)106 << 20)); // 16 MB
  f32x2* tab = (f32x2*)(ws + ((size_t)122 << 20));                   // 0.5 MB

  conv_x<<<8192, 256, 0, stream>>>(x, xbf, (B_ * L_ * D_) / 4);
  trans_w<<<dim3(4096 / 64, 1024 / 64), 256, 0, stream>>>(Wqkuv, Wt, 1024, 4096);
  trans_w<<<dim3(1024 / 64, 1024 / 64), 256, 0, stream>>>(Wout, Wot, 1024, 1024);
  rope_tab<<<(L_ * 32) / 256, 256, 0, stream>>>(tab);

  gemm_bf16<1><<<dim3(4096 / 256, 8192 / 256), 512, 0, stream>>>(xbf, Wt, qkuv_bf,
                                                                 B_ * L_, 4 * D_, D_);
  rope_conv<<<dim3(L_ / 64, B_ * H_), 256, 0, stream>>>(qkuv_bf, vt, tab);
  attn_mfma<<<dim3(L_ / 128, B_ * H_), 256, 0, stream>>>(qkuv_bf, vt, amask, cmask, cbias,
                                                         gamma, beta, attng);
  gemm_bf16<0><<<dim3(1024 / 256, 8192 / 256), 512, 0, stream>>>(attng, Wot, out,
                                                                 B_ * L_, D_, D_);
}

// Round 7
// 452.684 us; speedup vs baseline: 1.0784x; 1.0135x over previous
//
#include <hip/hip_runtime.h>
#include <math.h>
#include <stdint.h>

#define B_ 4
#define L_ 2048
#define D_ 1024
#define H_ 16

typedef __attribute__((ext_vector_type(4))) float f32x4;
typedef __attribute__((ext_vector_type(2))) float f32x2;
typedef __attribute__((ext_vector_type(8))) short s16x8;
typedef __attribute__((ext_vector_type(4))) short s16x4;
typedef __attribute__((ext_vector_type(4))) unsigned short u16x4;
typedef __attribute__((ext_vector_type(4))) unsigned int u32x4;
typedef __attribute__((ext_vector_type(2))) __bf16 bf16x2;

__device__ __forceinline__ unsigned short f2bf(float f) {
  unsigned int u = __float_as_uint(f);
  u += 0x7fffu + ((u >> 16) & 1u);  // RNE
  return (unsigned short)(u >> 16);
}
__device__ __forceinline__ float b2f(unsigned short s) {
  return __uint_as_float(((unsigned int)s) << 16);
}
// packed f32x2 -> bf16x2 (RTNE); lowers to v_cvt_pk_bf16_f32 on gfx950
__device__ __forceinline__ unsigned int pk2(float a, float b) {
  f32x2 v;
  v[0] = a;
  v[1] = b;
  bf16x2 r = __builtin_convertvector(v, bf16x2);
  return __builtin_bit_cast(unsigned int, r);
}
// silu via fast rcp (1-ulp)
__device__ __forceinline__ float silu_fast(float v) {
  return v * __builtin_amdgcn_rcpf(1.0f + __expf(-v));
}
// async global->LDS DMA, 16B per lane; lds dest = wave-uniform base + lane*16
__device__ __forceinline__ void gl_lds16(const void* g, void* l) {
  __builtin_amdgcn_global_load_lds(
      (__attribute__((address_space(1))) void*)(uintptr_t)g,
      (__attribute__((address_space(3))) void*)(uint32_t)(uintptr_t)l, 16, 0, 0);
}

// ---------------------------------------------------------------------------
// fp32 -> bf16 elementwise (x)
// ---------------------------------------------------------------------------
__global__ __launch_bounds__(256) void conv_x(const float* __restrict__ x,
                                              unsigned short* __restrict__ xb, int n4) {
  int i = blockIdx.x * 256 + threadIdx.x;
  if (i < n4) {
    f32x4 v = *(const f32x4*)(x + (size_t)i * 4);
    u16x4 o;
#pragma unroll
    for (int j = 0; j < 4; ++j) o[j] = f2bf(v[j]);
    *(u16x4*)(xb + (size_t)i * 4) = o;
  }
}

// ---------------------------------------------------------------------------
// W[K][N] fp32 -> Wt[N][K] bf16 (LDS tile transpose)
// ---------------------------------------------------------------------------
__global__ __launch_bounds__(256) void trans_w(const float* __restrict__ W,
                                               unsigned short* __restrict__ Wt,
                                               int K, int N) {
  __shared__ float T[64][65];
  const int k0 = blockIdx.y * 64, n0 = blockIdx.x * 64;
  const int tid = threadIdx.x;
#pragma unroll
  for (int i = 0; i < 16; ++i) {
    int e = tid + i * 256;
    int r = e >> 6, c = e & 63;
    T[r][c] = W[(size_t)(k0 + r) * N + n0 + c];
  }
  __syncthreads();
#pragma unroll
  for (int i = 0; i < 16; ++i) {
    int e = tid + i * 256;
    int r = e >> 6, c = e & 63;
    Wt[(size_t)(n0 + r) * K + k0 + c] = f2bf(T[c][r]);
  }
}

// ---------------------------------------------------------------------------
// RoPE cos/sin table [L][32]
// ---------------------------------------------------------------------------
__global__ __launch_bounds__(256) void rope_tab(f32x2* __restrict__ tab) {
  int i = blockIdx.x * 256 + threadIdx.x;  // L_*32
  int l = i >> 5, j = i & 31;
  float inv = expf(-(float)j * (9.210340371976184f / 32.0f));  // 10000^(-j/32)
  float ang = (float)l * inv;
  f32x2 cs;
  cs[0] = cosf(ang);
  cs[1] = sinf(ang);
  tab[i] = cs;
}

// ---------------------------------------------------------------------------
// bf16 MFMA GEMM 256x256 8-phase v2: COUNTED-vmcnt (T4).  C = [silu](A@Bt^T).
// Staging split into quadrant-matched groups (A-half qa, B-half qb; 2 DMAs/
// thread each) issued one group per phase of the PREVIOUS tile:
//   p0:A0'  p1:B0'  p2:A1'  p3:B1'
// Phase p consumes (A[p&1], B[p>>1]).  Per phase:
//   frag ds_reads || stage-issue -> barrier -> MFMA -> s_waitcnt vmcnt(N)
//   -> barrier
// The wait (own-DMA, counted) sits BEFORE the barrier after which the next
// phase consumes that group -> all waves' copies visible; loads never drain
// to 0 in steady state (m218: T3's gain IS T4; drain0 == 1-phase).
// Steady-state waits: vmcnt(4) at p0,p1,p3; none at p2.  Tail: 2/0.
// LDS XOR-8 chunk swizzle; XCD-chunked block swizzle.
// ---------------------------------------------------------------------------
template <int MODE>
__global__ __launch_bounds__(512) void gemm_bf16(const unsigned short* __restrict__ A,
                                                 const unsigned short* __restrict__ Bt,
                                                 void* __restrict__ Cp,
                                                 int M, int N, int K) {
  alignas(16) __shared__ unsigned short Ash[2][256][64];
  alignas(16) __shared__ unsigned short Bsh[2][256][64];
  const int tid = threadIdx.x;
  const int lane = tid & 63, w = tid >> 6;
  const int quad = lane >> 4, l15 = lane & 15;
  const int wm = w >> 2, wn = w & 3;  // 2 x 4 wave grid
  // XCD swizzle: physical wgid -> chunked logical id (8 XCDs round-robin)
  const int nwg = gridDim.x * gridDim.y;
  const int wgid = blockIdx.y * gridDim.x + blockIdx.x;
  const int swz = (wgid & 7) * (nwg >> 3) + (wgid >> 3);
  const int m0 = (swz / gridDim.x) * 256, n0 = (swz % gridDim.x) * 256;

  const int s_sub = lane >> 3;           // 0..7 row-within-8
  const int s_src = (lane & 7) ^ s_sub;  // source k-chunk (XOR-8 swizzle)

  // A-half qa: rows {qa*64..+63} U {128+qa*64..+63}  (2 DMAs/thread)
  auto stageA = [&](int k0, int qa, unsigned short(*dst)[64]) {
#pragma unroll
    for (int g = 0; g < 2; ++g) {
      int rb = qa * 64 + g * 128 + w * 8;  // wave-uniform
      gl_lds16(A + (size_t)(m0 + rb + s_sub) * K + k0 + s_src * 8, &dst[rb][0]);
    }
  };
  // B-half qb: rows r with (r&63) in [qb*32, qb*32+32)  (2 DMAs/thread)
  auto stageB = [&](int k0, int qb, unsigned short(*dst)[64]) {
#pragma unroll
    for (int g = 0; g < 2; ++g) {
      int rb = qb * 32 + g * 128 + (w >> 2) * 64 + (w & 3) * 8;  // wave-uniform
      gl_lds16(Bt + (size_t)(n0 + rb + s_sub) * K + k0 + s_src * 8, &dst[rb][0]);
    }
  };

  f32x4 acc[8][4] = {};
  const int NT = K / 64;

  // prologue: tile 0 all 4 groups in issue order A0,B0,A1,B1; wait A0,B0
  stageA(0, 0, Ash[0]);
  stageB(0, 0, Bsh[0]);
  stageA(0, 1, Ash[0]);
  stageB(0, 1, Bsh[0]);
  asm volatile("s_waitcnt vmcnt(4)" ::: "memory");
  __builtin_amdgcn_s_barrier();
  __builtin_amdgcn_sched_barrier(0);

  for (int t = 0; t < NT; ++t) {
    const int c = t & 1;
#pragma unroll
    for (int p = 0; p < 4; ++p) {
      const int qa = p & 1, qb = p >> 1;
      // frag ds_reads (current buffer, this phase's quadrant)
      s16x8 af[4][2], bf[2][2];
#pragma unroll
      for (int i = 0; i < 4; ++i)
#pragma unroll
        for (int ks = 0; ks < 2; ++ks)
          af[i][ks] = *(const s16x8*)&Ash[c][wm * 128 + (qa * 4 + i) * 16 + l15]
                                           [((ks * 4 + quad) ^ (l15 & 7)) * 8];
#pragma unroll
      for (int jn = 0; jn < 2; ++jn)
#pragma unroll
        for (int ks = 0; ks < 2; ++ks)
          bf[jn][ks] = *(const s16x8*)&Bsh[c][wn * 64 + (qb * 2 + jn) * 16 + l15]
                                            [((ks * 4 + quad) ^ (l15 & 7)) * 8];
      // issue this phase's stage group for tile t+1 into the alternate buffer
      if (t + 1 < NT) {
        if (p == 0) stageA((t + 1) * 64, 0, Ash[c ^ 1]);
        if (p == 1) stageB((t + 1) * 64, 0, Bsh[c ^ 1]);
        if (p == 2) stageA((t + 1) * 64, 1, Ash[c ^ 1]);
        if (p == 3) stageB((t + 1) * 64, 1, Bsh[c ^ 1]);
      }
      __builtin_amdgcn_sched_barrier(0);
      __builtin_amdgcn_s_barrier();
      __builtin_amdgcn_sched_barrier(0);
      __builtin_amdgcn_s_setprio(1);
#pragma unroll
      for (int i = 0; i < 4; ++i)
#pragma unroll
        for (int jn = 0; jn < 2; ++jn)
#pragma unroll
          for (int ks = 0; ks < 2; ++ks)
            acc[qa * 4 + i][qb * 2 + jn] = __builtin_amdgcn_mfma_f32_16x16x32_bf16(
                af[i][ks], bf[jn][ks], acc[qa * 4 + i][qb * 2 + jn], 0, 0, 0);
      __builtin_amdgcn_s_setprio(0);
      // counted wait: own-retire the group the NEXT phase consumes, BEFORE
      // the publishing barrier (never drain to 0 mid-loop)
      __builtin_amdgcn_sched_barrier(0);
      if (t + 1 < NT) {
        if (p != 2) asm volatile("s_waitcnt vmcnt(4)" ::: "memory");
      } else {
        if (p == 0) asm volatile("s_waitcnt vmcnt(2)" ::: "memory");
        if (p == 1) asm volatile("s_waitcnt vmcnt(0)" ::: "memory");
      }
      __builtin_amdgcn_s_barrier();
      __builtin_amdgcn_sched_barrier(0);
    }
  }

#pragma unroll
  for (int fm = 0; fm < 8; ++fm)
#pragma unroll
    for (int fn = 0; fn < 4; ++fn)
#pragma unroll
      for (int reg = 0; reg < 4; ++reg) {
        int rg = m0 + wm * 128 + fm * 16 + quad * 4 + reg;
        int cg = n0 + wn * 64 + fn * 16 + l15;
        float v = acc[fm][fn][reg];
        if (MODE == 1) {
          ((unsigned short*)Cp)[(size_t)rg * N + cg] = f2bf(silu_fast(v));
        } else {
          ((float*)Cp)[(size_t)rg * N + cg] = v;
        }
      }
}

// ---------------------------------------------------------------------------
// bf16 MFMA GEMM 128x128 (m97-structure + XCD swizzle) — used for gemm2
// (N=1024: 256-tile grid would be 128 blocks = half the CUs idle; 128-tile
// gives 512 blocks).  Proven in rounds 4-5.
// ---------------------------------------------------------------------------
template <int MODE>
__global__ __launch_bounds__(256) void gemm128_bf16(const unsigned short* __restrict__ A,
                                                    const unsigned short* __restrict__ Bt,
                                                    void* __restrict__ Cp,
                                                    int M, int N, int K) {
  alignas(16) __shared__ unsigned short As[128][32];
  alignas(16) __shared__ unsigned short Bs[128][32];
  const int tid = threadIdx.x;
  const int lane = tid & 63, w = tid >> 6;
  const int quad = lane >> 4, l15 = lane & 15;
  const int wr = w >> 1, wc = w & 1;
  const int nwg = gridDim.x * gridDim.y;
  const int wgid = blockIdx.y * gridDim.x + blockIdx.x;
  const int swz = (wgid & 7) * (nwg >> 3) + (wgid >> 3);
  const int m0 = (swz / gridDim.x) * 128, n0 = (swz % gridDim.x) * 128;
  const int srow = lane >> 2;
  const int schunk = (lane & 3) ^ ((lane >> 3) & 3);
  const int fcol = (quad ^ ((l15 >> 1) & 3)) * 8;
  f32x4 acc[4][4] = {};
  for (int k0 = 0; k0 < K; k0 += 32) {
    __syncthreads();
#pragma unroll
    for (int i = 0; i < 2; ++i) {
      int r0 = (w * 2 + i) * 16;
      gl_lds16(A + (size_t)(m0 + r0 + srow) * K + k0 + schunk * 8, &As[r0][0]);
      gl_lds16(Bt + (size_t)(n0 + r0 + srow) * K + k0 + schunk * 8, &Bs[r0][0]);
    }
    __syncthreads();
    s16x8 af[4], bf[4];
#pragma unroll
    for (int mi = 0; mi < 4; ++mi) af[mi] = *(const s16x8*)&As[wr * 64 + mi * 16 + l15][fcol];
#pragma unroll
    for (int nj = 0; nj < 4; ++nj) bf[nj] = *(const s16x8*)&Bs[wc * 64 + nj * 16 + l15][fcol];
#pragma unroll
    for (int mi = 0; mi < 4; ++mi)
#pragma unroll
      for (int nj = 0; nj < 4; ++nj)
        acc[mi][nj] = __builtin_amdgcn_mfma_f32_16x16x32_bf16(af[mi], bf[nj], acc[mi][nj], 0, 0, 0);
  }
#pragma unroll
  for (int mi = 0; mi < 4; ++mi)
#pragma unroll
    for (int nj = 0; nj < 4; ++nj)
#pragma unroll
      for (int reg = 0; reg < 4; ++reg) {
        int rg = m0 + wr * 64 + mi * 16 + quad * 4 + reg;
        int cg = n0 + wc * 64 + nj * 16 + l15;
        float v = acc[mi][nj][reg];
        if (MODE == 1) {
          ((unsigned short*)Cp)[(size_t)rg * N + cg] = f2bf(silu_fast(v));
        } else {
          ((float*)Cp)[(size_t)rg * N + cg] = v;
        }
      }
}

// ---------------------------------------------------------------------------
// In-place RoPE on q,k quarters of qkuv_bf + build v_t[bh][64 d][Lperm] bf16.
// Key axis of vt is PERMUTED within each 32-group so that P fragments (C-layout
// of S^T, pairs of 16-key tiles concatenated) form a valid mfma_16x16x32
// A-operand: position p = 8q+4h+j  <-  local key 16h+4q+j.
// ---------------------------------------------------------------------------
__global__ __launch_bounds__(256) void rope_conv(unsigned short* __restrict__ qk,
                                                 unsigned short* __restrict__ vt,
                                                 const f32x2* __restrict__ tab) {
  alignas(16) __shared__ unsigned short Vsh[64][72];
  const int tid = threadIdx.x;
  const int bh = blockIdx.y, b = bh >> 4, h = bh & 15;
  const int l0 = blockIdx.x * 64;
#pragma unroll
  for (int i = 0; i < 2; ++i) {
    int p = tid + i * 256;
    int row = p >> 3, c4 = p & 7;
    int l = l0 + row;
    size_t base = (size_t)(b * L_ + l) * 4096 + h * 64 + c4 * 4;
#pragma unroll
    for (int t = 0; t < 2; ++t) {  // 0: q, 1: k
      size_t o = base + (size_t)t * 1024;
      u16x4 lo = *(u16x4*)(qk + o);
      u16x4 hi = *(u16x4*)(qk + o + 32);
      u16x4 nlo, nhi;
#pragma unroll
      for (int jj = 0; jj < 4; ++jj) {
        f32x2 cs = tab[l * 32 + c4 * 4 + jj];
        float fl = b2f(lo[jj]), fh = b2f(hi[jj]);
        nlo[jj] = f2bf(fl * cs[0] - fh * cs[1]);
        nhi[jj] = f2bf(fh * cs[0] + fl * cs[1]);
      }
      *(u16x4*)(qk + o) = nlo;
      *(u16x4*)(qk + o + 32) = nhi;
    }
  }
#pragma unroll
  for (int i = 0; i < 2; ++i) {
    int ch = tid + i * 256;
    int row = ch >> 3, c8 = ch & 7;
    *(s16x8*)&Vsh[row][c8 * 8] =
        *(const s16x8*)(qk + (size_t)(b * L_ + l0 + row) * 4096 + 2048 + h * 64 + c8 * 8);
  }
  __syncthreads();
#pragma unroll
  for (int i = 0; i < 2; ++i) {
    int ch = tid + i * 256;
    int drow = ch >> 3, c8 = ch & 7;
    s16x8 o;
#pragma unroll
    for (int jj = 0; jj < 8; ++jj) {
      int pos = c8 * 8 + jj;  // 0..63 within tile
      int g = pos >> 5, p = pos & 31;
      int lk = g * 32 + ((p >> 2) & 1) * 16 + ((p >> 3) & 3) * 4 + (p & 3);
      o[jj] = (short)Vsh[lk][drow];
    }
    *(s16x8*)(vt + (size_t)(bh * 64 + drow) * 2048 + l0 + c8 * 8) = o;
  }
}

// ---------------------------------------------------------------------------
// Fused MFMA attention v4 (round-0 baseline — protected at ~210us; six probe
// rounds showed it at a local optimum).
// ---------------------------------------------------------------------------
__global__ __launch_bounds__(256) void attn_mfma(
    const unsigned short* __restrict__ qk, const unsigned short* __restrict__ vt,
    const float* __restrict__ amask, const float* __restrict__ cmask,
    const float* __restrict__ cbias, const float* __restrict__ gamma,
    const float* __restrict__ beta, unsigned short* __restrict__ attng) {
  alignas(16) __shared__ unsigned short Ks[64][64];   // [key][d], d-chunks XORed
  alignas(16) __shared__ unsigned short Vts[64][64];  // [d][key], key-chunks XORed
  const int tid = threadIdx.x;
  const int lane = tid & 63, w = tid >> 6;
  const int quad = lane >> 4, l15 = lane & 15;
  const int bh = blockIdx.y, b = bh >> 4, h = bh & 15;
  const int l0 = blockIdx.x * 128;
  const float cb = cbias[h];
  const int srow = lane >> 3;            // 0..7 within a 1KB DMA
  const int schunk = (lane & 7) ^ srow;  // source chunk for XOR-8 store

  // Hoist Q fragments for this wave's 32 q-rows (b-operand of S^T mfma)
  s16x8 qf[2][2];
  const float* abase[2];
#pragma unroll
  for (int qs = 0; qs < 2; ++qs) {
    int qg = l0 + w * 32 + qs * 16 + l15;
#pragma unroll
    for (int s = 0; s < 2; ++s)
      qf[qs][s] = *(const s16x8*)(qk + (size_t)(b * L_ + qg) * 4096 + h * 64 + s * 32 + quad * 8);
    abase[qs] = amask + ((size_t)b * L_ + qg) * L_;
  }
  const float* cbase = cmask + (size_t)b * L_;

  f32x4 oacc[2][4] = {};  // [qs][dt] C-layout: row=q=quad*4+reg, col=d=dt*16+l15

  for (int m0 = 0; m0 < L_; m0 += 64) {
    __syncthreads();  // prev-iter LDS reads complete before DMA overwrite
#pragma unroll
    for (int i = 0; i < 2; ++i) {  // wave w stages rows w*16+i*8 .. +7
      int r0 = w * 16 + i * 8;
      gl_lds16(qk + (size_t)(b * L_ + m0 + r0 + srow) * 4096 + 1024 + h * 64 + schunk * 8,
               &Ks[r0][0]);
      gl_lds16(vt + (size_t)(bh * 64 + r0 + srow) * 2048 + m0 + schunk * 8, &Vts[r0][0]);
    }
    // Masks: one vaddr per qs, 4 imm-offset loads each
    f32x4 cmcb[4], am4[2][4];
#pragma unroll
    for (int kt = 0; kt < 4; ++kt)
      cmcb[kt] = *(const f32x4*)(cbase + m0 + kt * 16 + quad * 4) * cb;
#pragma unroll
    for (int qs = 0; qs < 2; ++qs)
#pragma unroll
      for (int kt = 0; kt < 4; ++kt)
        am4[qs][kt] = *(const f32x4*)(abase[qs] + m0 + kt * 16 + quad * 4);
    __syncthreads();  // vmcnt(0) drain -> DMA + mask loads complete

    // S^T = K @ Q^T over d=64 (two K=32 steps)
    f32x4 sacc[2][4] = {};  // [qs][kt]; C: key=quad*4+reg, q=l15
#pragma unroll
    for (int s = 0; s < 2; ++s) {
      s16x8 kf[4];
#pragma unroll
      for (int kt = 0; kt < 4; ++kt)
        kf[kt] = *(const s16x8*)&Ks[kt * 16 + l15][((s * 4 + quad) ^ (l15 & 7)) * 8];
      __builtin_amdgcn_s_setprio(1);
#pragma unroll
      for (int qs = 0; qs < 2; ++qs)
#pragma unroll
        for (int kt = 0; kt < 4; ++kt)
          sacc[qs][kt] = __builtin_amdgcn_mfma_f32_16x16x32_bf16(kf[kt], qf[qs][s],
                                                                 sacc[qs][kt], 0, 0, 0);
      __builtin_amdgcn_s_setprio(0);
    }

    // Epilogue -> P fragments packed as K=32 A-operands (kt pairs)
    s16x8 pf[2][2];
#pragma unroll
    for (int qs = 0; qs < 2; ++qs)
#pragma unroll
      for (int t = 0; t < 2; ++t) {
        u32x4 pw;
#pragma unroll
        for (int half = 0; half < 2; ++half) {
          int kt = 2 * t + half;
          float x[4];
#pragma unroll
          for (int r = 0; r < 4; ++r) {
            float v = fmaf(sacc[qs][kt][r], 0.125f, cmcb[kt][r]);
            v = silu_fast(v);
            x[r] = v * am4[qs][kt][r];
          }
          pw[half * 2 + 0] = pk2(x[0], x[1]);
          pw[half * 2 + 1] = pk2(x[2], x[3]);
        }
        pf[qs][t] = __builtin_bit_cast(s16x8, pw);
      }

    // O += P @ V, K=32 per group (vt key-permuted to match P's lane layout)
#pragma unroll
    for (int dt = 0; dt < 4; ++dt)
#pragma unroll
      for (int t = 0; t < 2; ++t) {
        s16x8 vf = *(const s16x8*)&Vts[dt * 16 + l15][((t * 4 + quad) ^ (l15 & 7)) * 8];
        __builtin_amdgcn_s_setprio(1);
#pragma unroll
        for (int qs = 0; qs < 2; ++qs)
          oacc[qs][dt] = __builtin_amdgcn_mfma_f32_16x16x32_bf16(pf[qs][t], vf,
                                                                 oacc[qs][dt], 0, 0, 0);
        __builtin_amdgcn_s_setprio(0);
      }
  }

  // LayerNorm over d=64 + u-gate + store
#pragma unroll
  for (int qs = 0; qs < 2; ++qs) {
    float sm[4], sq[4];
#pragma unroll
    for (int reg = 0; reg < 4; ++reg) {
      float s1 = 0.f, s2 = 0.f;
#pragma unroll
      for (int dt = 0; dt < 4; ++dt) {
        float v = oacc[qs][dt][reg];
        s1 += v;
        s2 += v * v;
      }
      sm[reg] = s1;
      sq[reg] = s2;
    }
#pragma unroll
    for (int m = 1; m < 16; m <<= 1) {
#pragma unroll
      for (int reg = 0; reg < 4; ++reg) {
        sm[reg] += __shfl_xor(sm[reg], m);
        sq[reg] += __shfl_xor(sq[reg], m);
      }
    }
    float mu[4], rs[4];
#pragma unroll
    for (int reg = 0; reg < 4; ++reg) {
      mu[reg] = sm[reg] * (1.0f / 64.0f);
      float var = sq[reg] * (1.0f / 64.0f) - mu[reg] * mu[reg];
      rs[reg] = rsqrtf(var + 1e-5f);
    }
#pragma unroll
    for (int dt = 0; dt < 4; ++dt) {
      float g = gamma[dt * 16 + l15], be = beta[dt * 16 + l15];
#pragma unroll
      for (int reg = 0; reg < 4; ++reg) {
        int rowg = l0 + w * 32 + qs * 16 + quad * 4 + reg;
        int colg = dt * 16 + l15;
        float v = (oacc[qs][dt][reg] - mu[reg]) * rs[reg] * g + be;
        float u = b2f(qk[(size_t)(b * L_ + rowg) * 4096 + 3072 + h * 64 + colg]);
        attng[(size_t)(b * L_ + rowg) * 1024 + h * 64 + colg] = f2bf(v * u);
      }
    }
  }
}

extern "C" void kernel_launch(void* const* d_in, const int* in_sizes, int n_in,
                              void* d_out, int out_size, void* d_ws, size_t ws_size,
                              hipStream_t stream) {
  const float* x = (const float*)d_in[0];
  const float* amask = (const float*)d_in[1];
  const float* cmask = (const float*)d_in[2];
  const float* Wqkuv = (const float*)d_in[3];
  const float* Wout = (const float*)d_in[4];
  const float* gamma = (const float*)d_in[5];
  const float* beta = (const float*)d_in[6];
  const float* cbias = (const float*)d_in[7];
  float* out = (float*)d_out;

  char* ws = (char*)d_ws;
  unsigned short* qkuv_bf = (unsigned short*)ws;                    // 64 MB
  unsigned short* vt = (unsigned short*)(ws + ((size_t)64 << 20));  // 16 MB
  unsigned short* xbf = (unsigned short*)(ws + ((size_t)80 << 20));  // 16 MB
  unsigned short* Wt = (unsigned short*)(ws + ((size_t)96 << 20));   // 8 MB
  unsigned short* Wot = (unsigned short*)(ws + ((size_t)104 << 20)); // 2 MB
  unsigned short* attng = (unsigned short*)(ws + ((size_t)106 << 20)); // 16 MB
  f32x2* tab = (f32x2*)(ws + ((size_t)122 << 20));                   // 0.5 MB

  conv_x<<<8192, 256, 0, stream>>>(x, xbf, (B_ * L_ * D_) / 4);
  trans_w<<<dim3(4096 / 64, 1024 / 64), 256, 0, stream>>>(Wqkuv, Wt, 1024, 4096);
  trans_w<<<dim3(1024 / 64, 1024 / 64), 256, 0, stream>>>(Wout, Wot, 1024, 1024);
  rope_tab<<<(L_ * 32) / 256, 256, 0, stream>>>(tab);

  gemm_bf16<1><<<dim3(4096 / 256, 8192 / 256), 512, 0, stream>>>(xbf, Wt, qkuv_bf,
                                                                 B_ * L_, 4 * D_, D_);
  rope_conv<<<dim3(L_ / 64, B_ * H_), 256, 0, stream>>>(qkuv_bf, vt, tab);
  attn_mfma<<<dim3(L_ / 128, B_ * H_), 256, 0, stream>>>(qkuv_bf, vt, amask, cmask, cbias,
                                                         gamma, beta, attng);
  gemm128_bf16<0><<<dim3(1024 / 128, 8192 / 128), 256, 0, stream>>>(attng, Wot, out,
                                                                    B_ * L_, D_, D_);
}

// Round 8
// 445.076 us; speedup vs baseline: 1.0968x; 1.0171x over previous
//
#include <hip/hip_runtime.h>
#include <math.h>
#include <stdint.h>

#define B_ 4
#define L_ 2048
#define D_ 1024
#define H_ 16

typedef __attribute__((ext_vector_type(4))) float f32x4;
typedef __attribute__((ext_vector_type(2))) float f32x2;
typedef __attribute__((ext_vector_type(8))) short s16x8;
typedef __attribute__((ext_vector_type(4))) short s16x4;
typedef __attribute__((ext_vector_type(4))) unsigned short u16x4;
typedef __attribute__((ext_vector_type(4))) unsigned int u32x4;
typedef __attribute__((ext_vector_type(2))) __bf16 bf16x2;

__device__ __forceinline__ unsigned short f2bf(float f) {
  unsigned int u = __float_as_uint(f);
  u += 0x7fffu + ((u >> 16) & 1u);  // RNE
  return (unsigned short)(u >> 16);
}
__device__ __forceinline__ float b2f(unsigned short s) {
  return __uint_as_float(((unsigned int)s) << 16);
}
// packed f32x2 -> bf16x2 (RTNE); lowers to v_cvt_pk_bf16_f32 on gfx950
__device__ __forceinline__ unsigned int pk2(float a, float b) {
  f32x2 v;
  v[0] = a;
  v[1] = b;
  bf16x2 r = __builtin_convertvector(v, bf16x2);
  return __builtin_bit_cast(unsigned int, r);
}
// silu via fast rcp (1-ulp)
__device__ __forceinline__ float silu_fast(float v) {
  return v * __builtin_amdgcn_rcpf(1.0f + __expf(-v));
}
// async global->LDS DMA, 16B per lane; lds dest = wave-uniform base + lane*16
__device__ __forceinline__ void gl_lds16(const void* g, void* l) {
  __builtin_amdgcn_global_load_lds(
      (__attribute__((address_space(1))) void*)(uintptr_t)g,
      (__attribute__((address_space(3))) void*)(uint32_t)(uintptr_t)l, 16, 0, 0);
}

// ---------------------------------------------------------------------------
// Merged prep: conv_x (8192 blocks) | trans_w Wqkuv (1024) | trans_w Wout
// (256) | rope_tab (256).  All independent; one launch kills 3 launch gaps.
// ---------------------------------------------------------------------------
__global__ __launch_bounds__(256) void prep(const float* __restrict__ x,
                                            unsigned short* __restrict__ xb,
                                            const float* __restrict__ Wqkuv,
                                            unsigned short* __restrict__ Wt,
                                            const float* __restrict__ Wout,
                                            unsigned short* __restrict__ Wot,
                                            f32x2* __restrict__ tab) {
  const int bid = blockIdx.x;
  const int tid = threadIdx.x;
  if (bid < 8192) {
    // conv_x: fp32 -> bf16 (x), 4 elems/thread
    int i = bid * 256 + tid;
    f32x4 v = *(const f32x4*)(x + (size_t)i * 4);
    u16x4 o;
#pragma unroll
    for (int j = 0; j < 4; ++j) o[j] = f2bf(v[j]);
    *(u16x4*)(xb + (size_t)i * 4) = o;
  } else if (bid < 9472) {
    // W[K][N] fp32 -> Wt[N][K] bf16 (LDS tile transpose)
    __shared__ float T[64][65];
    const float* W;
    unsigned short* Wd;
    int K, N, bx, by;
    if (bid < 9216) {
      int e = bid - 8192;  // grid (64,16) over (N=4096,K=1024)
      W = Wqkuv; Wd = Wt; K = 1024; N = 4096; bx = e & 63; by = e >> 6;
    } else {
      int e = bid - 9216;  // grid (16,16) over (N=1024,K=1024)
      W = Wout; Wd = Wot; K = 1024; N = 1024; bx = e & 15; by = e >> 4;
    }
    const int k0 = by * 64, n0 = bx * 64;
#pragma unroll
    for (int i = 0; i < 16; ++i) {
      int e = tid + i * 256;
      int r = e >> 6, c = e & 63;
      T[r][c] = W[(size_t)(k0 + r) * N + n0 + c];
    }
    __syncthreads();
#pragma unroll
    for (int i = 0; i < 16; ++i) {
      int e = tid + i * 256;
      int r = e >> 6, c = e & 63;
      Wd[(size_t)(n0 + r) * K + k0 + c] = f2bf(T[c][r]);
    }
  } else {
    // rope_tab: cos/sin table [L][32]
    int i = (bid - 9472) * 256 + tid;  // L_*32
    int l = i >> 5, j = i & 31;
    float inv = expf(-(float)j * (9.210340371976184f / 32.0f));  // 10000^(-j/32)
    float ang = (float)l * inv;
    f32x2 cs;
    cs[0] = cosf(ang);
    cs[1] = sinf(ang);
    tab[i] = cs;
  }
}

// ---------------------------------------------------------------------------
// bf16 MFMA GEMM 256x256 8-phase, counted-vmcnt (T4) — unchanged structure
// from round 7.  NEW: fused RoPE in the epilogue.  For blocks with n0<2048
// (the q,k quarters), the rotation pair (head-col c, c+32) lives in the SAME
// lane: acc[fm][fn] pairs with acc[fm][fn^2].  Apply rope(silu(v)) in f32
// before the single bf16 quantization (strictly more accurate than the old
// silu->bf16->rope->bf16 path) using tab[l*32 + (fn&1)*16 + l15].
// ---------------------------------------------------------------------------
template <int MODE>
__global__ __launch_bounds__(512) void gemm_bf16(const unsigned short* __restrict__ A,
                                                 const unsigned short* __restrict__ Bt,
                                                 void* __restrict__ Cp,
                                                 const f32x2* __restrict__ tab,
                                                 int M, int N, int K) {
  alignas(16) __shared__ unsigned short Ash[2][256][64];
  alignas(16) __shared__ unsigned short Bsh[2][256][64];
  const int tid = threadIdx.x;
  const int lane = tid & 63, w = tid >> 6;
  const int quad = lane >> 4, l15 = lane & 15;
  const int wm = w >> 2, wn = w & 3;  // 2 x 4 wave grid
  // XCD swizzle: physical wgid -> chunked logical id (8 XCDs round-robin)
  const int nwg = gridDim.x * gridDim.y;
  const int wgid = blockIdx.y * gridDim.x + blockIdx.x;
  const int swz = (wgid & 7) * (nwg >> 3) + (wgid >> 3);
  const int m0 = (swz / gridDim.x) * 256, n0 = (swz % gridDim.x) * 256;

  const int s_sub = lane >> 3;           // 0..7 row-within-8
  const int s_src = (lane & 7) ^ s_sub;  // source k-chunk (XOR-8 swizzle)

  auto stageA = [&](int k0, int qa, unsigned short(*dst)[64]) {
#pragma unroll
    for (int g = 0; g < 2; ++g) {
      int rb = qa * 64 + g * 128 + w * 8;  // wave-uniform
      gl_lds16(A + (size_t)(m0 + rb + s_sub) * K + k0 + s_src * 8, &dst[rb][0]);
    }
  };
  auto stageB = [&](int k0, int qb, unsigned short(*dst)[64]) {
#pragma unroll
    for (int g = 0; g < 2; ++g) {
      int rb = qb * 32 + g * 128 + (w >> 2) * 64 + (w & 3) * 8;  // wave-uniform
      gl_lds16(Bt + (size_t)(n0 + rb + s_sub) * K + k0 + s_src * 8, &dst[rb][0]);
    }
  };

  f32x4 acc[8][4] = {};
  const int NT = K / 64;

  // prologue: tile 0 all 4 groups in issue order A0,B0,A1,B1; wait A0,B0
  stageA(0, 0, Ash[0]);
  stageB(0, 0, Bsh[0]);
  stageA(0, 1, Ash[0]);
  stageB(0, 1, Bsh[0]);
  asm volatile("s_waitcnt vmcnt(4)" ::: "memory");
  __builtin_amdgcn_s_barrier();
  __builtin_amdgcn_sched_barrier(0);

  for (int t = 0; t < NT; ++t) {
    const int c = t & 1;
#pragma unroll
    for (int p = 0; p < 4; ++p) {
      const int qa = p & 1, qb = p >> 1;
      s16x8 af[4][2], bf[2][2];
#pragma unroll
      for (int i = 0; i < 4; ++i)
#pragma unroll
        for (int ks = 0; ks < 2; ++ks)
          af[i][ks] = *(const s16x8*)&Ash[c][wm * 128 + (qa * 4 + i) * 16 + l15]
                                           [((ks * 4 + quad) ^ (l15 & 7)) * 8];
#pragma unroll
      for (int jn = 0; jn < 2; ++jn)
#pragma unroll
        for (int ks = 0; ks < 2; ++ks)
          bf[jn][ks] = *(const s16x8*)&Bsh[c][wn * 64 + (qb * 2 + jn) * 16 + l15]
                                            [((ks * 4 + quad) ^ (l15 & 7)) * 8];
      if (t + 1 < NT) {
        if (p == 0) stageA((t + 1) * 64, 0, Ash[c ^ 1]);
        if (p == 1) stageB((t + 1) * 64, 0, Bsh[c ^ 1]);
        if (p == 2) stageA((t + 1) * 64, 1, Ash[c ^ 1]);
        if (p == 3) stageB((t + 1) * 64, 1, Bsh[c ^ 1]);
      }
      __builtin_amdgcn_sched_barrier(0);
      __builtin_amdgcn_s_barrier();
      __builtin_amdgcn_sched_barrier(0);
      __builtin_amdgcn_s_setprio(1);
#pragma unroll
      for (int i = 0; i < 4; ++i)
#pragma unroll
        for (int jn = 0; jn < 2; ++jn)
#pragma unroll
          for (int ks = 0; ks < 2; ++ks)
            acc[qa * 4 + i][qb * 2 + jn] = __builtin_amdgcn_mfma_f32_16x16x32_bf16(
                af[i][ks], bf[jn][ks], acc[qa * 4 + i][qb * 2 + jn], 0, 0, 0);
      __builtin_amdgcn_s_setprio(0);
      __builtin_amdgcn_sched_barrier(0);
      if (t + 1 < NT) {
        if (p != 2) asm volatile("s_waitcnt vmcnt(4)" ::: "memory");
      } else {
        if (p == 0) asm volatile("s_waitcnt vmcnt(2)" ::: "memory");
        if (p == 1) asm volatile("s_waitcnt vmcnt(0)" ::: "memory");
      }
      __builtin_amdgcn_s_barrier();
      __builtin_amdgcn_sched_barrier(0);
    }
  }

  if (MODE == 1 && n0 < 2048) {
    // q/k quarters: silu then in-register RoPE, single bf16 quantization.
    // Head-local col = fn*16 + l15 (wn*64 is head-aligned); j = (fn&1)*16+l15;
    // lo half fn<2 pairs with hi half fn+2 (same lane, same j).
#pragma unroll
    for (int fm = 0; fm < 8; ++fm)
#pragma unroll
      for (int reg = 0; reg < 4; ++reg) {
        int rg = m0 + wm * 128 + fm * 16 + quad * 4 + reg;
        int l = rg & (L_ - 1);
        f32x2 cs0 = tab[l * 32 + l15];
        f32x2 cs1 = tab[l * 32 + 16 + l15];
        float v0 = silu_fast(acc[fm][0][reg]);
        float v1 = silu_fast(acc[fm][1][reg]);
        float v2 = silu_fast(acc[fm][2][reg]);
        float v3 = silu_fast(acc[fm][3][reg]);
        unsigned short* rowp = (unsigned short*)Cp + (size_t)rg * N + n0 + wn * 64 + l15;
        rowp[0] = f2bf(v0 * cs0[0] - v2 * cs0[1]);
        rowp[16] = f2bf(v1 * cs1[0] - v3 * cs1[1]);
        rowp[32] = f2bf(v2 * cs0[0] + v0 * cs0[1]);
        rowp[48] = f2bf(v3 * cs1[0] + v1 * cs1[1]);
      }
  } else {
#pragma unroll
    for (int fm = 0; fm < 8; ++fm)
#pragma unroll
      for (int fn = 0; fn < 4; ++fn)
#pragma unroll
        for (int reg = 0; reg < 4; ++reg) {
          int rg = m0 + wm * 128 + fm * 16 + quad * 4 + reg;
          int cg = n0 + wn * 64 + fn * 16 + l15;
          float v = acc[fm][fn][reg];
          if (MODE == 1) {
            ((unsigned short*)Cp)[(size_t)rg * N + cg] = f2bf(silu_fast(v));
          } else {
            ((float*)Cp)[(size_t)rg * N + cg] = v;
          }
        }
  }
}

// ---------------------------------------------------------------------------
// bf16 MFMA GEMM 128x128 (m97-structure + XCD swizzle) — gemm2 (N=1024:
// 512 blocks vs 128 for the 256-tile).  Proven rounds 4-7.
// ---------------------------------------------------------------------------
template <int MODE>
__global__ __launch_bounds__(256) void gemm128_bf16(const unsigned short* __restrict__ A,
                                                    const unsigned short* __restrict__ Bt,
                                                    void* __restrict__ Cp,
                                                    int M, int N, int K) {
  alignas(16) __shared__ unsigned short As[128][32];
  alignas(16) __shared__ unsigned short Bs[128][32];
  const int tid = threadIdx.x;
  const int lane = tid & 63, w = tid >> 6;
  const int quad = lane >> 4, l15 = lane & 15;
  const int wr = w >> 1, wc = w & 1;
  const int nwg = gridDim.x * gridDim.y;
  const int wgid = blockIdx.y * gridDim.x + blockIdx.x;
  const int swz = (wgid & 7) * (nwg >> 3) + (wgid >> 3);
  const int m0 = (swz / gridDim.x) * 128, n0 = (swz % gridDim.x) * 128;
  const int srow = lane >> 2;
  const int schunk = (lane & 3) ^ ((lane >> 3) & 3);
  const int fcol = (quad ^ ((l15 >> 1) & 3)) * 8;
  f32x4 acc[4][4] = {};
  for (int k0 = 0; k0 < K; k0 += 32) {
    __syncthreads();
#pragma unroll
    for (int i = 0; i < 2; ++i) {
      int r0 = (w * 2 + i) * 16;
      gl_lds16(A + (size_t)(m0 + r0 + srow) * K + k0 + schunk * 8, &As[r0][0]);
      gl_lds16(Bt + (size_t)(n0 + r0 + srow) * K + k0 + schunk * 8, &Bs[r0][0]);
    }
    __syncthreads();
    s16x8 af[4], bf[4];
#pragma unroll
    for (int mi = 0; mi < 4; ++mi) af[mi] = *(const s16x8*)&As[wr * 64 + mi * 16 + l15][fcol];
#pragma unroll
    for (int nj = 0; nj < 4; ++nj) bf[nj] = *(const s16x8*)&Bs[wc * 64 + nj * 16 + l15][fcol];
#pragma unroll
    for (int mi = 0; mi < 4; ++mi)
#pragma unroll
      for (int nj = 0; nj < 4; ++nj)
        acc[mi][nj] = __builtin_amdgcn_mfma_f32_16x16x32_bf16(af[mi], bf[nj], acc[mi][nj], 0, 0, 0);
  }
#pragma unroll
  for (int mi = 0; mi < 4; ++mi)
#pragma unroll
    for (int nj = 0; nj < 4; ++nj)
#pragma unroll
      for (int reg = 0; reg < 4; ++reg) {
        int rg = m0 + wr * 64 + mi * 16 + quad * 4 + reg;
        int cg = n0 + wc * 64 + nj * 16 + l15;
        float v = acc[mi][nj][reg];
        if (MODE == 1) {
          ((unsigned short*)Cp)[(size_t)rg * N + cg] = f2bf(silu_fast(v));
        } else {
          ((float*)Cp)[(size_t)rg * N + cg] = v;
        }
      }
}

// ---------------------------------------------------------------------------
// vt build only (RoPE now fused into gemm1): v_t[bh][64 d][Lperm] bf16 with
// the PV key permutation p = 8q+4h+j <- local key 16h+4q+j.
// ---------------------------------------------------------------------------
__global__ __launch_bounds__(256) void vt_build(const unsigned short* __restrict__ qk,
                                                unsigned short* __restrict__ vt) {
  alignas(16) __shared__ unsigned short Vsh[64][72];
  const int tid = threadIdx.x;
  const int bh = blockIdx.y, b = bh >> 4, h = bh & 15;
  const int l0 = blockIdx.x * 64;
#pragma unroll
  for (int i = 0; i < 2; ++i) {
    int ch = tid + i * 256;
    int row = ch >> 3, c8 = ch & 7;
    *(s16x8*)&Vsh[row][c8 * 8] =
        *(const s16x8*)(qk + (size_t)(b * L_ + l0 + row) * 4096 + 2048 + h * 64 + c8 * 8);
  }
  __syncthreads();
#pragma unroll
  for (int i = 0; i < 2; ++i) {
    int ch = tid + i * 256;
    int drow = ch >> 3, c8 = ch & 7;
    s16x8 o;
#pragma unroll
    for (int jj = 0; jj < 8; ++jj) {
      int pos = c8 * 8 + jj;  // 0..63 within tile
      int g = pos >> 5, p = pos & 31;
      int lk = g * 32 + ((p >> 2) & 1) * 16 + ((p >> 3) & 3) * 4 + (p & 3);
      o[jj] = (short)Vsh[lk][drow];
    }
    *(s16x8*)(vt + (size_t)(bh * 64 + drow) * 2048 + l0 + c8 * 8) = o;
  }
}

// ---------------------------------------------------------------------------
// Fused MFMA attention v4 (round-0 baseline — protected at ~210us; six probe
// rounds showed it at a local optimum).
// ---------------------------------------------------------------------------
__global__ __launch_bounds__(256) void attn_mfma(
    const unsigned short* __restrict__ qk, const unsigned short* __restrict__ vt,
    const float* __restrict__ amask, const float* __restrict__ cmask,
    const float* __restrict__ cbias, const float* __restrict__ gamma,
    const float* __restrict__ beta, unsigned short* __restrict__ attng) {
  alignas(16) __shared__ unsigned short Ks[64][64];   // [key][d], d-chunks XORed
  alignas(16) __shared__ unsigned short Vts[64][64];  // [d][key], key-chunks XORed
  const int tid = threadIdx.x;
  const int lane = tid & 63, w = tid >> 6;
  const int quad = lane >> 4, l15 = lane & 15;
  const int bh = blockIdx.y, b = bh >> 4, h = bh & 15;
  const int l0 = blockIdx.x * 128;
  const float cb = cbias[h];
  const int srow = lane >> 3;            // 0..7 within a 1KB DMA
  const int schunk = (lane & 7) ^ srow;  // source chunk for XOR-8 store

  // Hoist Q fragments for this wave's 32 q-rows (b-operand of S^T mfma)
  s16x8 qf[2][2];
  const float* abase[2];
#pragma unroll
  for (int qs = 0; qs < 2; ++qs) {
    int qg = l0 + w * 32 + qs * 16 + l15;
#pragma unroll
    for (int s = 0; s < 2; ++s)
      qf[qs][s] = *(const s16x8*)(qk + (size_t)(b * L_ + qg) * 4096 + h * 64 + s * 32 + quad * 8);
    abase[qs] = amask + ((size_t)b * L_ + qg) * L_;
  }
  const float* cbase = cmask + (size_t)b * L_;

  f32x4 oacc[2][4] = {};  // [qs][dt] C-layout: row=q=quad*4+reg, col=d=dt*16+l15

  for (int m0 = 0; m0 < L_; m0 += 64) {
    __syncthreads();  // prev-iter LDS reads complete before DMA overwrite
#pragma unroll
    for (int i = 0; i < 2; ++i) {  // wave w stages rows w*16+i*8 .. +7
      int r0 = w * 16 + i * 8;
      gl_lds16(qk + (size_t)(b * L_ + m0 + r0 + srow) * 4096 + 1024 + h * 64 + schunk * 8,
               &Ks[r0][0]);
      gl_lds16(vt + (size_t)(bh * 64 + r0 + srow) * 2048 + m0 + schunk * 8, &Vts[r0][0]);
    }
    // Masks: one vaddr per qs, 4 imm-offset loads each
    f32x4 cmcb[4], am4[2][4];
#pragma unroll
    for (int kt = 0; kt < 4; ++kt)
      cmcb[kt] = *(const f32x4*)(cbase + m0 + kt * 16 + quad * 4) * cb;
#pragma unroll
    for (int qs = 0; qs < 2; ++qs)
#pragma unroll
      for (int kt = 0; kt < 4; ++kt)
        am4[qs][kt] = *(const f32x4*)(abase[qs] + m0 + kt * 16 + quad * 4);
    __syncthreads();  // vmcnt(0) drain -> DMA + mask loads complete

    // S^T = K @ Q^T over d=64 (two K=32 steps)
    f32x4 sacc[2][4] = {};  // [qs][kt]; C: key=quad*4+reg, q=l15
#pragma unroll
    for (int s = 0; s < 2; ++s) {
      s16x8 kf[4];
#pragma unroll
      for (int kt = 0; kt < 4; ++kt)
        kf[kt] = *(const s16x8*)&Ks[kt * 16 + l15][((s * 4 + quad) ^ (l15 & 7)) * 8];
      __builtin_amdgcn_s_setprio(1);
#pragma unroll
      for (int qs = 0; qs < 2; ++qs)
#pragma unroll
        for (int kt = 0; kt < 4; ++kt)
          sacc[qs][kt] = __builtin_amdgcn_mfma_f32_16x16x32_bf16(kf[kt], qf[qs][s],
                                                                 sacc[qs][kt], 0, 0, 0);
      __builtin_amdgcn_s_setprio(0);
    }

    // Epilogue -> P fragments packed as K=32 A-operands (kt pairs)
    s16x8 pf[2][2];
#pragma unroll
    for (int qs = 0; qs < 2; ++qs)
#pragma unroll
      for (int t = 0; t < 2; ++t) {
        u32x4 pw;
#pragma unroll
        for (int half = 0; half < 2; ++half) {
          int kt = 2 * t + half;
          float x[4];
#pragma unroll
          for (int r = 0; r < 4; ++r) {
            float v = fmaf(sacc[qs][kt][r], 0.125f, cmcb[kt][r]);
            v = silu_fast(v);
            x[r] = v * am4[qs][kt][r];
          }
          pw[half * 2 + 0] = pk2(x[0], x[1]);
          pw[half * 2 + 1] = pk2(x[2], x[3]);
        }
        pf[qs][t] = __builtin_bit_cast(s16x8, pw);
      }

    // O += P @ V, K=32 per group (vt key-permuted to match P's lane layout)
#pragma unroll
    for (int dt = 0; dt < 4; ++dt)
#pragma unroll
      for (int t = 0; t < 2; ++t) {
        s16x8 vf = *(const s16x8*)&Vts[dt * 16 + l15][((t * 4 + quad) ^ (l15 & 7)) * 8];
        __builtin_amdgcn_s_setprio(1);
#pragma unroll
        for (int qs = 0; qs < 2; ++qs)
          oacc[qs][dt] = __builtin_amdgcn_mfma_f32_16x16x32_bf16(pf[qs][t], vf,
                                                                 oacc[qs][dt], 0, 0, 0);
        __builtin_amdgcn_s_setprio(0);
      }
  }

  // LayerNorm over d=64 + u-gate + store
#pragma unroll
  for (int qs = 0; qs < 2; ++qs) {
    float sm[4], sq[4];
#pragma unroll
    for (int reg = 0; reg < 4; ++reg) {
      float s1 = 0.f, s2 = 0.f;
#pragma unroll
      for (int dt = 0; dt < 4; ++dt) {
        float v = oacc[qs][dt][reg];
        s1 += v;
        s2 += v * v;
      }
      sm[reg] = s1;
      sq[reg] = s2;
    }
#pragma unroll
    for (int m = 1; m < 16; m <<= 1) {
#pragma unroll
      for (int reg = 0; reg < 4; ++reg) {
        sm[reg] += __shfl_xor(sm[reg], m);
        sq[reg] += __shfl_xor(sq[reg], m);
      }
    }
    float mu[4], rs[4];
#pragma unroll
    for (int reg = 0; reg < 4; ++reg) {
      mu[reg] = sm[reg] * (1.0f / 64.0f);
      float var = sq[reg] * (1.0f / 64.0f) - mu[reg] * mu[reg];
      rs[reg] = rsqrtf(var + 1e-5f);
    }
#pragma unroll
    for (int dt = 0; dt < 4; ++dt) {
      float g = gamma[dt * 16 + l15], be = beta[dt * 16 + l15];
#pragma unroll
      for (int reg = 0; reg < 4; ++reg) {
        int rowg = l0 + w * 32 + qs * 16 + quad * 4 + reg;
        int colg = dt * 16 + l15;
        float v = (oacc[qs][dt][reg] - mu[reg]) * rs[reg] * g + be;
        float u = b2f(qk[(size_t)(b * L_ + rowg) * 4096 + 3072 + h * 64 + colg]);
        attng[(size_t)(b * L_ + rowg) * 1024 + h * 64 + colg] = f2bf(v * u);
      }
    }
  }
}

extern "C" void kernel_launch(void* const* d_in, const int* in_sizes, int n_in,
                              void* d_out, int out_size, void* d_ws, size_t ws_size,
                              hipStream_t stream) {
  const float* x = (const float*)d_in[0];
  const float* amask = (const float*)d_in[1];
  const float* cmask = (const float*)d_in[2];
  const float* Wqkuv = (const float*)d_in[3];
  const float* Wout = (const float*)d_in[4];
  const float* gamma = (const float*)d_in[5];
  const float* beta = (const float*)d_in[6];
  const float* cbias = (const float*)d_in[7];
  float* out = (float*)d_out;

  char* ws = (char*)d_ws;
  unsigned short* qkuv_bf = (unsigned short*)ws;                    // 64 MB
  unsigned short* vt = (unsigned short*)(ws + ((size_t)64 << 20));  // 16 MB
  unsigned short* xbf = (unsigned short*)(ws + ((size_t)80 << 20));  // 16 MB
  unsigned short* Wt = (unsigned short*)(ws + ((size_t)96 << 20));   // 8 MB
  unsigned short* Wot = (unsigned short*)(ws + ((size_t)104 << 20)); // 2 MB
  unsigned short* attng = (unsigned short*)(ws + ((size_t)106 << 20)); // 16 MB
  f32x2* tab = (f32x2*)(ws + ((size_t)122 << 20));                   // 0.5 MB

  prep<<<9728, 256, 0, stream>>>(x, xbf, Wqkuv, Wt, Wout, Wot, tab);

  gemm_bf16<1><<<dim3(4096 / 256, 8192 / 256), 512, 0, stream>>>(xbf, Wt, qkuv_bf, tab,
                                                                 B_ * L_, 4 * D_, D_);
  vt_build<<<dim3(L_ / 64, B_ * H_), 256, 0, stream>>>(qkuv_bf, vt);
  attn_mfma<<<dim3(L_ / 128, B_ * H_), 256, 0, stream>>>(qkuv_bf, vt, amask, cmask, cbias,
                                                         gamma, beta, attng);
  gemm128_bf16<0><<<dim3(1024 / 128, 8192 / 128), 256, 0, stream>>>(attng, Wot, out,
                                                                    B_ * L_, D_, D_);
}